// Round 1
// baseline (894.072 us; speedup 1.0000x reference)
//
#include <hip/hip_runtime.h>

// Complex MultiheadAttention, fp16-MFMA implementation for gfx950.
// E=512 H=8 D=64 T=S=2048 B=4. All shapes divide tile sizes exactly.

typedef _Float16 half8 __attribute__((ext_vector_type(8)));
typedef float f32x4 __attribute__((ext_vector_type(4)));
typedef float f32x2 __attribute__((ext_vector_type(2)));

__device__ __forceinline__ f32x4 mfma16(half8 a, half8 b, f32x4 c) {
  return __builtin_amdgcn_mfma_f32_16x16x32_f16(a, b, c, 0, 0, 0);
}

__device__ __forceinline__ half8 cvt8(f32x4 a, f32x4 b) {
  half8 h;
  h[0] = (_Float16)a[0]; h[1] = (_Float16)a[1]; h[2] = (_Float16)a[2]; h[3] = (_Float16)a[3];
  h[4] = (_Float16)b[0]; h[5] = (_Float16)b[1]; h[6] = (_Float16)b[2]; h[7] = (_Float16)b[3];
  return h;
}

__device__ __forceinline__ half8 neg8(half8 a) {
  half8 r;
#pragma unroll
  for (int i = 0; i < 8; i++) r[i] = -a[i];
  return r;
}

// ---------------- kernel 0: convert weights fp32 -> fp16 into ws ----------------
// layout (half elements): [0) in_w_r 786432 | in_w_i 786432 | out_w_r 262144 | out_w_i 262144
__global__ __launch_bounds__(256) void cvt_weights_kernel(
    const float* __restrict__ iwr, const float* __restrict__ iwi,
    const float* __restrict__ owr, const float* __restrict__ owi,
    _Float16* __restrict__ dst) {
  const int i = blockIdx.x * 256 + threadIdx.x;  // 262144 threads, 8 elems each
  const float* src;
  long so, doff;
  if (i < 98304)       { src = iwr; so = (long)i * 8;            doff = so; }
  else if (i < 196608) { src = iwi; so = (long)(i - 98304) * 8;  doff = 786432 + so; }
  else if (i < 229376) { src = owr; so = (long)(i - 196608) * 8; doff = 1572864 + so; }
  else                 { src = owi; so = (long)(i - 229376) * 8; doff = 1835008 + so; }
  f32x4 a = *(const f32x4*)(src + so);
  f32x4 b = *(const f32x4*)(src + so + 4);
  *(half8*)(dst + doff) = cvt8(a, b);
}

// ---------------- kernel 1: in-projection complex GEMM ----------------
// C(8192x512) = X(8192x512) @ W(512x512)^T per proj (q,k,v), complex.
// grid (128, 8, 3), block 256 (4 waves, each wave a 16x64 strip).
__global__ __launch_bounds__(256) void inproj_kernel(
    const float* __restrict__ xqr, const float* __restrict__ xqi,
    const float* __restrict__ xkr, const float* __restrict__ xki,
    const float* __restrict__ xvr, const float* __restrict__ xvi,
    const _Float16* __restrict__ wr, const _Float16* __restrict__ wi,   // (1536,512) fp16
    const float* __restrict__ br_, const float* __restrict__ bi_,      // (1536)
    _Float16* __restrict__ qr, _Float16* __restrict__ qi,              // (8192,512)
    _Float16* __restrict__ kr, _Float16* __restrict__ ki,              // (8192,512)
    _Float16* __restrict__ vtr, _Float16* __restrict__ vti) {          // (B,E,S) transposed
  const int proj = blockIdx.z;
  const float* xr = (proj == 0) ? xqr : (proj == 1) ? xkr : xvr;
  const float* xi = (proj == 0) ? xqi : (proj == 1) ? xki : xvi;
  const int lane = threadIdx.x & 63, wave = threadIdx.x >> 6;
  const int c = lane & 15, g = lane >> 4;
  const int m0 = blockIdx.x * 64 + wave * 16;
  const int n0 = blockIdx.y * 64;

  f32x4 accR[4] = {};
  f32x4 accI[4] = {};
  const float* xrp = xr + (long)(m0 + c) * 512 + g * 8;
  const float* xip = xi + (long)(m0 + c) * 512 + g * 8;
  const _Float16* wrp = wr + (long)(proj * 512 + n0 + c) * 512 + g * 8;
  const _Float16* wip = wi + (long)(proj * 512 + n0 + c) * 512 + g * 8;

  for (int kk = 0; kk < 512; kk += 32) {
    f32x4 x0 = *(const f32x4*)(xrp + kk);
    f32x4 x1 = *(const f32x4*)(xrp + kk + 4);
    f32x4 y0 = *(const f32x4*)(xip + kk);
    f32x4 y1 = *(const f32x4*)(xip + kk + 4);
    half8 ar = cvt8(x0, x1);
    half8 ai = cvt8(y0, y1);
    half8 nai = neg8(ai);
#pragma unroll
    for (int nt = 0; nt < 4; nt++) {
      half8 bR = *(const half8*)(wrp + nt * 16 * 512 + kk);
      half8 bI = *(const half8*)(wip + nt * 16 * 512 + kk);
      accR[nt] = mfma16(ar, bR, accR[nt]);
      accR[nt] = mfma16(nai, bI, accR[nt]);   // yr = xr*wr - xi*wi
      accI[nt] = mfma16(ar, bI, accI[nt]);
      accI[nt] = mfma16(ai, bR, accI[nt]);    // yi = xr*wi + xi*wr
    }
  }
#pragma unroll
  for (int nt = 0; nt < 4; nt++) {
    const int n = n0 + nt * 16 + c;
    const float vbr = br_[proj * 512 + n];
    const float vbi = bi_[proj * 512 + n];
#pragma unroll
    for (int r = 0; r < 4; r++) {
      const int m = m0 + g * 4 + r;                 // D row = 4*(lane>>4)+reg
      const float yr = accR[nt][r] + vbr;
      const float yi = accI[nt][r] + vbi;
      if (proj == 0) {
        qr[(long)m * 512 + n] = (_Float16)yr;
        qi[(long)m * 512 + n] = (_Float16)yi;
      } else if (proj == 1) {
        kr[(long)m * 512 + n] = (_Float16)yr;
        ki[(long)m * 512 + n] = (_Float16)yi;
      } else {
        const int bb = m & 3, s = m >> 2;           // m = s*B + b
        vtr[(long)(bb * 512 + n) * 2048 + s] = (_Float16)yr;
        vti[(long)(bb * 512 + n) * 2048 + s] = (_Float16)yi;
      }
    }
  }
}

// ---------------- kernel 2: softmax pass 1 (row max m, row sumexp l) ----------------
// swapped MFMA: D[s][t] = mfma(K, Q) so each lane owns one t-row (t = lane&15).
// grid (32, 8, 4) = (T/64, H, B), block 256 (4 waves x 16 t-rows).
__global__ __launch_bounds__(256) void pass1_kernel(
    const _Float16* __restrict__ qr, const _Float16* __restrict__ qi,
    const _Float16* __restrict__ kr, const _Float16* __restrict__ ki,
    float* __restrict__ m_out, float* __restrict__ r_out) {
  const int lane = threadIdx.x & 63, wave = threadIdx.x >> 6;
  const int c = lane & 15, g = lane >> 4;
  const int t0 = blockIdx.x * 64 + wave * 16;
  const int h = blockIdx.y, b = blockIdx.z;
  const float SC2 = 0.18033688011112042f;  // log2(e)/sqrt(64)

  const long qoff = (long)((t0 + c) * 4 + b) * 512 + h * 64 + g * 8;
  const half8 qf00 = *(const half8*)(qr + qoff);
  const half8 qf01 = *(const half8*)(qi + qoff);
  const half8 qf10 = *(const half8*)(qr + qoff + 32);
  const half8 qf11 = *(const half8*)(qi + qoff + 32);

  float mrun = -1e30f, lrun = 0.0f;
  const _Float16* krp = kr + (long)(c * 4 + b) * 512 + h * 64 + g * 8;
  const _Float16* kip = ki + (long)(c * 4 + b) * 512 + h * 64 + g * 8;

  for (int s0 = 0; s0 < 2048; s0 += 32) {
    const long o0 = (long)s0 * 2048;
    const long o1 = (long)(s0 + 16) * 2048;
    half8 a00 = *(const half8*)(krp + o0);
    half8 a01 = *(const half8*)(kip + o0);
    half8 a02 = *(const half8*)(krp + o0 + 32);
    half8 a03 = *(const half8*)(kip + o0 + 32);
    half8 a10 = *(const half8*)(krp + o1);
    half8 a11 = *(const half8*)(kip + o1);
    half8 a12 = *(const half8*)(krp + o1 + 32);
    half8 a13 = *(const half8*)(kip + o1 + 32);
    f32x4 acc0 = {0.f, 0.f, 0.f, 0.f}, acc1 = {0.f, 0.f, 0.f, 0.f};
    acc0 = mfma16(a00, qf00, acc0);   // Re[QK^H] = qr*kr + qi*ki
    acc0 = mfma16(a01, qf01, acc0);
    acc0 = mfma16(a02, qf10, acc0);
    acc0 = mfma16(a03, qf11, acc0);
    acc1 = mfma16(a10, qf00, acc1);
    acc1 = mfma16(a11, qf01, acc1);
    acc1 = mfma16(a12, qf10, acc1);
    acc1 = mfma16(a13, qf11, acc1);
    float s2[8];
#pragma unroll
    for (int r = 0; r < 4; r++) { s2[r] = acc0[r] * SC2; s2[4 + r] = acc1[r] * SC2; }
    float tm = s2[0];
#pragma unroll
    for (int j = 1; j < 8; j++) tm = fmaxf(tm, s2[j]);
    const float nm = fmaxf(mrun, tm);
    float sum = 0.0f;
#pragma unroll
    for (int j = 0; j < 8; j++) sum += exp2f(s2[j] - nm);
    lrun = lrun * exp2f(mrun - nm) + sum;
    mrun = nm;
  }
  // combine the 4 lane-groups holding disjoint s-subsets of the same t-row
#pragma unroll
  for (int off = 16; off <= 32; off <<= 1) {
    const float mo = __shfl_xor(mrun, off, 64);
    const float lo = __shfl_xor(lrun, off, 64);
    const float nm = fmaxf(mrun, mo);
    lrun = lrun * exp2f(mrun - nm) + lo * exp2f(mo - nm);
    mrun = nm;
  }
  if (lane < 16) {
    const int idx = (b * 8 + h) * 2048 + t0 + c;
    m_out[idx] = mrun;
    r_out[idx] = 1.0f / lrun;
  }
}

// ---------------- kernel 3: softmax pass 2 + attn mean + PV ----------------
// grid (64, 4) = (T/32, B), block 512 = 8 waves = 8 heads. One block per CU.
__global__ __launch_bounds__(512, 2) void pass2_kernel(
    const _Float16* __restrict__ qr, const _Float16* __restrict__ qi,
    const _Float16* __restrict__ kr, const _Float16* __restrict__ ki,
    const _Float16* __restrict__ vtr, const _Float16* __restrict__ vti,
    const float* __restrict__ m_in, const float* __restrict__ r_in,
    _Float16* __restrict__ orh, _Float16* __restrict__ oih,
    float* __restrict__ attn) {
  __shared__ _Float16 plds[8][32][40];   // [head][t_local][s_local], stride-40 pad
  const int lane = threadIdx.x & 63, h = threadIdx.x >> 6;
  const int c = lane & 15, g = lane >> 4;
  const int t0 = blockIdx.x * 32;
  const int b = blockIdx.y;
  const float SC2 = 0.18033688011112042f;

  half8 qf[2][2][2];  // [strip][dchunk][ri]
#pragma unroll
  for (int st = 0; st < 2; st++) {
    const long qoff = (long)((t0 + st * 16 + c) * 4 + b) * 512 + h * 64 + g * 8;
    qf[st][0][0] = *(const half8*)(qr + qoff);
    qf[st][0][1] = *(const half8*)(qi + qoff);
    qf[st][1][0] = *(const half8*)(qr + qoff + 32);
    qf[st][1][1] = *(const half8*)(qi + qoff + 32);
  }
  float mrow[2][4], rrow[2][4];
#pragma unroll
  for (int st = 0; st < 2; st++)
#pragma unroll
    for (int r = 0; r < 4; r++) {
      const int idx = (b * 8 + h) * 2048 + t0 + st * 16 + g * 4 + r;
      mrow[st][r] = m_in[idx];
      rrow[st][r] = r_in[idx];
    }
  f32x4 oacc[2][4][2] = {};  // [strip][dtile][ri]
  const _Float16* krp = kr + (long)(c * 4 + b) * 512 + h * 64 + g * 8;
  const _Float16* kip = ki + (long)(c * 4 + b) * 512 + h * 64 + g * 8;
  const _Float16* vrp = vtr + (long)(b * 512 + h * 64 + c) * 2048 + g * 8;
  const _Float16* vip = vti + (long)(b * 512 + h * 64 + c) * 2048 + g * 8;

  for (int s0 = 0; s0 < 2048; s0 += 32) {
    // --- scores for this head (non-swapped: D[t][s]) ---
    half8 kf[2][2][2];  // [stile][dchunk][ri]
#pragma unroll
    for (int stile = 0; stile < 2; stile++) {
      const long koff = (long)(s0 + stile * 16) * 2048;
      kf[stile][0][0] = *(const half8*)(krp + koff);
      kf[stile][0][1] = *(const half8*)(kip + koff);
      kf[stile][1][0] = *(const half8*)(krp + koff + 32);
      kf[stile][1][1] = *(const half8*)(kip + koff + 32);
    }
    f32x4 sacc[2][2] = {};
#pragma unroll
    for (int st = 0; st < 2; st++)
#pragma unroll
      for (int stile = 0; stile < 2; stile++) {
        f32x4 a = sacc[st][stile];
        a = mfma16(qf[st][0][0], kf[stile][0][0], a);
        a = mfma16(qf[st][0][1], kf[stile][0][1], a);
        a = mfma16(qf[st][1][0], kf[stile][1][0], a);
        a = mfma16(qf[st][1][1], kf[stile][1][1], a);
        sacc[st][stile] = a;
      }
    // --- p = exp2(s*SC2 - m) * (1/l), write fp16 to LDS ---
#pragma unroll
    for (int st = 0; st < 2; st++)
#pragma unroll
      for (int stile = 0; stile < 2; stile++)
#pragma unroll
        for (int r = 0; r < 4; r++) {
          const float p = exp2f(sacc[st][stile][r] * SC2 - mrow[st][r]) * rrow[st][r];
          plds[h][st * 16 + g * 4 + r][stile * 16 + c] = (_Float16)p;
        }
    __syncthreads();
    // --- PV: A = p (from LDS, a-frag layout), B = V^T slice (contiguous) ---
    half8 vf[4][2];
#pragma unroll
    for (int dt = 0; dt < 4; dt++) {
      vf[dt][0] = *(const half8*)(vrp + (long)dt * 16 * 2048 + s0);
      vf[dt][1] = *(const half8*)(vip + (long)dt * 16 * 2048 + s0);
    }
#pragma unroll
    for (int st = 0; st < 2; st++) {
      const half8 pf = *(const half8*)(&plds[h][st * 16 + c][g * 8]);
#pragma unroll
      for (int dt = 0; dt < 4; dt++) {
        oacc[st][dt][0] = mfma16(pf, vf[dt][0], oacc[st][dt][0]);
        oacc[st][dt][1] = mfma16(pf, vf[dt][1], oacc[st][dt][1]);
      }
    }
    // --- attn_weights = mean over heads, written once (block owns (b,t,s) tile) ---
    {
      const int tt = threadIdx.x >> 4;
      const int sp = (threadIdx.x & 15) * 2;
      float a0 = 0.f, a1 = 0.f;
#pragma unroll
      for (int w = 0; w < 8; w++) {
        a0 += (float)plds[w][tt][sp];
        a1 += (float)plds[w][tt][sp + 1];
      }
      f32x2 out2 = {a0 * 0.125f, a1 * 0.125f};
      *(f32x2*)(attn + (long)(b * 2048 + t0 + tt) * 2048 + s0 + sp) = out2;
    }
    __syncthreads();
  }
  // --- epilogue: write attention output (fp16, (T*B, E) rows) ---
#pragma unroll
  for (int st = 0; st < 2; st++)
#pragma unroll
    for (int dt = 0; dt < 4; dt++)
#pragma unroll
      for (int r = 0; r < 4; r++) {
        const int t = t0 + st * 16 + g * 4 + r;
        const long row = (long)(t * 4 + b) * 512 + h * 64 + dt * 16 + c;
        orh[row] = (_Float16)oacc[st][dt][0][r];
        oih[row] = (_Float16)oacc[st][dt][1][r];
      }
}

// ---------------- kernel 4: out-projection complex GEMM -> fp32 d_out ----------------
// grid (128, 8), block 256 (4 waves x 16x64 strips).
__global__ __launch_bounds__(256) void outproj_kernel(
    const _Float16* __restrict__ xr, const _Float16* __restrict__ xi,   // (8192,512)
    const _Float16* __restrict__ wr, const _Float16* __restrict__ wi,   // (512,512)
    const float* __restrict__ br_, const float* __restrict__ bi_,
    float* __restrict__ outr, float* __restrict__ outi) {
  const int lane = threadIdx.x & 63, wave = threadIdx.x >> 6;
  const int c = lane & 15, g = lane >> 4;
  const int m0 = blockIdx.x * 64 + wave * 16;
  const int n0 = blockIdx.y * 64;
  f32x4 accR[4] = {};
  f32x4 accI[4] = {};
  const _Float16* xrp = xr + (long)(m0 + c) * 512 + g * 8;
  const _Float16* xip = xi + (long)(m0 + c) * 512 + g * 8;
  const _Float16* wrp = wr + (long)(n0 + c) * 512 + g * 8;
  const _Float16* wip = wi + (long)(n0 + c) * 512 + g * 8;
  for (int kk = 0; kk < 512; kk += 32) {
    half8 ar = *(const half8*)(xrp + kk);
    half8 ai = *(const half8*)(xip + kk);
    half8 nai = neg8(ai);
#pragma unroll
    for (int nt = 0; nt < 4; nt++) {
      half8 bR = *(const half8*)(wrp + nt * 16 * 512 + kk);
      half8 bI = *(const half8*)(wip + nt * 16 * 512 + kk);
      accR[nt] = mfma16(ar, bR, accR[nt]);
      accR[nt] = mfma16(nai, bI, accR[nt]);
      accI[nt] = mfma16(ar, bI, accI[nt]);
      accI[nt] = mfma16(ai, bR, accI[nt]);
    }
  }
#pragma unroll
  for (int nt = 0; nt < 4; nt++) {
    const int n = n0 + nt * 16 + c;
    const float vbr = br_[n], vbi = bi_[n];
#pragma unroll
    for (int r = 0; r < 4; r++) {
      const int m = m0 + g * 4 + r;
      outr[(long)m * 512 + n] = accR[nt][r] + vbr;
      outi[(long)m * 512 + n] = accI[nt][r] + vbi;
    }
  }
}

extern "C" void kernel_launch(void* const* d_in, const int* in_sizes, int n_in,
                              void* d_out, int out_size, void* d_ws, size_t ws_size,
                              hipStream_t stream) {
  const float* query_r = (const float*)d_in[0];
  const float* query_i = (const float*)d_in[1];
  const float* key_r   = (const float*)d_in[2];
  const float* key_i   = (const float*)d_in[3];
  const float* value_r = (const float*)d_in[4];
  const float* value_i = (const float*)d_in[5];
  const float* in_w_r  = (const float*)d_in[6];
  const float* in_w_i  = (const float*)d_in[7];
  const float* in_b_r  = (const float*)d_in[8];
  const float* in_b_i  = (const float*)d_in[9];
  const float* out_w_r = (const float*)d_in[10];
  const float* out_w_i = (const float*)d_in[11];
  const float* out_b_r = (const float*)d_in[12];
  const float* out_b_i = (const float*)d_in[13];

  // workspace layout (fp16 elements)
  _Float16* ws = (_Float16*)d_ws;
  _Float16* w16_inr  = ws;                   // 786432
  _Float16* w16_ini  = ws + 786432;          // 786432
  _Float16* w16_outr = ws + 1572864;         // 262144
  _Float16* w16_outi = ws + 1835008;         // 262144
  _Float16* qr  = ws + 2097152;              // 8 arrays x 4194304
  _Float16* qi  = qr  + 4194304;
  _Float16* kr  = qi  + 4194304;
  _Float16* ki  = kr  + 4194304;
  _Float16* vtr = ki  + 4194304;
  _Float16* vti = vtr + 4194304;
  _Float16* orh = vti + 4194304;
  _Float16* oih = orh + 4194304;
  float* m_arr = (float*)(oih + 4194304);    // 65536 fp32
  float* r_arr = m_arr + 65536;              // 65536 fp32  (total ~71.8 MB)

  float* outr = (float*)d_out;               // (T,B,E)
  float* outi = outr + 4194304;              // (T,B,E)
  float* attn = outr + 8388608;              // (B,T,S)

  cvt_weights_kernel<<<1024, 256, 0, stream>>>(in_w_r, in_w_i, out_w_r, out_w_i, ws);

  inproj_kernel<<<dim3(128, 8, 3), 256, 0, stream>>>(
      query_r, query_i, key_r, key_i, value_r, value_i,
      w16_inr, w16_ini, in_b_r, in_b_i,
      qr, qi, kr, ki, vtr, vti);

  pass1_kernel<<<dim3(32, 8, 4), 256, 0, stream>>>(qr, qi, kr, ki, m_arr, r_arr);

  pass2_kernel<<<dim3(64, 4), 512, 0, stream>>>(
      qr, qi, kr, ki, vtr, vti, m_arr, r_arr, orh, oih, attn);

  outproj_kernel<<<dim3(128, 8), 256, 0, stream>>>(
      orh, oih, w16_outr, w16_outi, out_b_r, out_b_i, outr, outi);
}

// Round 2
// 659.087 us; speedup vs baseline: 1.3565x; 1.3565x over previous
//
#include <hip/hip_runtime.h>

// Complex MultiheadAttention, fp16-MFMA implementation for gfx950.
// E=512 H=8 D=64 T=S=2048 B=4. All shapes divide tile sizes exactly.

typedef _Float16 half8 __attribute__((ext_vector_type(8)));
typedef float f32x4 __attribute__((ext_vector_type(4)));
typedef float f32x2 __attribute__((ext_vector_type(2)));

__device__ __forceinline__ f32x4 mfma16(half8 a, half8 b, f32x4 c) {
  return __builtin_amdgcn_mfma_f32_16x16x32_f16(a, b, c, 0, 0, 0);
}

__device__ __forceinline__ half8 cvt8(f32x4 a, f32x4 b) {
  half8 h;
  h[0] = (_Float16)a[0]; h[1] = (_Float16)a[1]; h[2] = (_Float16)a[2]; h[3] = (_Float16)a[3];
  h[4] = (_Float16)b[0]; h[5] = (_Float16)b[1]; h[6] = (_Float16)b[2]; h[7] = (_Float16)b[3];
  return h;
}

__device__ __forceinline__ half8 neg8(half8 a) {
  half8 r;
#pragma unroll
  for (int i = 0; i < 8; i++) r[i] = -a[i];
  return r;
}

__device__ __forceinline__ void gload16(const void* g, void* l) {
  __builtin_amdgcn_global_load_lds((const __attribute__((address_space(1))) void*)g,
                                   (__attribute__((address_space(3))) void*)l, 16, 0, 0);
}

// ---------------- kernel 0: convert weights fp32 -> fp16 into ws ----------------
__global__ __launch_bounds__(256) void cvt_weights_kernel(
    const float* __restrict__ iwr, const float* __restrict__ iwi,
    const float* __restrict__ owr, const float* __restrict__ owi,
    _Float16* __restrict__ dst) {
  const int i = blockIdx.x * 256 + threadIdx.x;  // 262144 threads, 8 elems each
  const float* src;
  long so, doff;
  if (i < 98304)       { src = iwr; so = (long)i * 8;            doff = so; }
  else if (i < 196608) { src = iwi; so = (long)(i - 98304) * 8;  doff = 786432 + so; }
  else if (i < 229376) { src = owr; so = (long)(i - 196608) * 8; doff = 1572864 + so; }
  else                 { src = owi; so = (long)(i - 229376) * 8; doff = 1835008 + so; }
  f32x4 a = *(const f32x4*)(src + so);
  f32x4 b = *(const f32x4*)(src + so + 4);
  *(half8*)(dst + doff) = cvt8(a, b);
}

// ---------------- kernel 1: in-projection complex GEMM (m97 structure) ----------------
// C(8192x512) = X(8192x512) @ W(512x512)^T per proj, complex.
// 128x128 block tile, BK=32, 4 waves each 64x64, global_load_lds staging.
// LDS XOR-swizzled via pre-swizzled global source + swizzled ds_read (involution).
// grid (64, 4, 3), block 256.
__global__ __launch_bounds__(256, 2) void inproj_kernel(
    const float* __restrict__ xqr, const float* __restrict__ xqi,
    const float* __restrict__ xkr, const float* __restrict__ xki,
    const float* __restrict__ xvr, const float* __restrict__ xvi,
    const _Float16* __restrict__ wr, const _Float16* __restrict__ wi,   // (1536,512) fp16
    const float* __restrict__ br_, const float* __restrict__ bi_,      // (1536)
    _Float16* __restrict__ qr, _Float16* __restrict__ qi,              // (8192,512)
    _Float16* __restrict__ kr, _Float16* __restrict__ ki,              // (8192,512)
    _Float16* __restrict__ vtr, _Float16* __restrict__ vti) {          // (B,E,S) transposed
  __shared__ float As_r[4096], As_i[4096];       // [128][32] f32, swizzled
  __shared__ _Float16 Bs_r[4096], Bs_i[4096];    // [128][32] f16, swizzled
  const int proj = blockIdx.z;
  const float* xr = (proj == 0) ? xqr : (proj == 1) ? xkr : xvr;
  const float* xi = (proj == 0) ? xqi : (proj == 1) ? xki : xvi;
  const int lane = threadIdx.x & 63, wave = threadIdx.x >> 6;
  const int c = lane & 15, g = lane >> 4;
  const int wrow = (wave >> 1) * 64, wcol = (wave & 1) * 64;
  const int m0 = blockIdx.x * 128, n0 = blockIdx.y * 128;

  // pre-swizzled staging source column offsets (lane constants)
  const int acol = ((lane & 7) ^ (lane >> 3)) * 4;        // f32 units
  const int bcol = ((lane & 3) ^ ((lane >> 3) & 3)) * 8;  // f16 units
  // read-side swizzle constants
  const int sa = (c & 7) << 2;                            // f32 units
  const int sb = ((c >> 1) & 3) << 3;                     // f16 units

  f32x4 accR[4][4] = {};
  f32x4 accI[4][4] = {};

#pragma unroll 1
  for (int kk = 0; kk < 512; kk += 32) {
    // ---- stage A (fp32, 4 insts/wave per matrix) ----
#pragma unroll
    for (int q = 0; q < 4; q++) {
      const int grp = wave * 4 + q;
      const int arow = grp * 8 + (lane >> 3);
      const long go = (long)(m0 + arow) * 512 + kk + acol;
      gload16(xr + go, &As_r[grp * 256]);
      gload16(xi + go, &As_i[grp * 256]);
    }
    // ---- stage B (fp16, 2 insts/wave per matrix) ----
#pragma unroll
    for (int q = 0; q < 2; q++) {
      const int grp = wave * 2 + q;
      const int brow = grp * 16 + (lane >> 2);
      const long go = (long)(proj * 512 + n0 + brow) * 512 + kk + bcol;
      gload16(wr + go, &Bs_r[grp * 512]);
      gload16(wi + go, &Bs_i[grp * 512]);
    }
    __syncthreads();
    // ---- LDS -> fragments ----
    half8 a_r[4], a_i[4], a_ni[4];
#pragma unroll
    for (int mt = 0; mt < 4; mt++) {
      const int arow = wrow + mt * 16 + c;
      f32x4 lo = *(const f32x4*)&As_r[arow * 32 + ((g * 8) ^ sa)];
      f32x4 hi = *(const f32x4*)&As_r[arow * 32 + ((g * 8 + 4) ^ sa)];
      a_r[mt] = cvt8(lo, hi);
      lo = *(const f32x4*)&As_i[arow * 32 + ((g * 8) ^ sa)];
      hi = *(const f32x4*)&As_i[arow * 32 + ((g * 8 + 4) ^ sa)];
      a_i[mt] = cvt8(lo, hi);
      a_ni[mt] = neg8(a_i[mt]);
    }
    // ---- MFMA ----
#pragma unroll
    for (int nt = 0; nt < 4; nt++) {
      const int brow = wcol + nt * 16 + c;
      const half8 bR = *(const half8*)&Bs_r[brow * 32 + ((g * 8) ^ sb)];
      const half8 bI = *(const half8*)&Bs_i[brow * 32 + ((g * 8) ^ sb)];
#pragma unroll
      for (int mt = 0; mt < 4; mt++) {
        accR[mt][nt] = mfma16(a_r[mt], bR, accR[mt][nt]);
        accR[mt][nt] = mfma16(a_ni[mt], bI, accR[mt][nt]);  // yr = xr*wr - xi*wi
        accI[mt][nt] = mfma16(a_r[mt], bI, accI[mt][nt]);
        accI[mt][nt] = mfma16(a_i[mt], bR, accI[mt][nt]);   // yi = xr*wi + xi*wr
      }
    }
    __syncthreads();
  }
  // ---- epilogue ----
#pragma unroll
  for (int nt = 0; nt < 4; nt++) {
    const int n = n0 + wcol + nt * 16 + c;
    const float vbr = br_[proj * 512 + n];
    const float vbi = bi_[proj * 512 + n];
#pragma unroll
    for (int mt = 0; mt < 4; mt++)
#pragma unroll
      for (int r = 0; r < 4; r++) {
        const int m = m0 + wrow + mt * 16 + g * 4 + r;
        const float yr = accR[mt][nt][r] + vbr;
        const float yi = accI[mt][nt][r] + vbi;
        if (proj == 0) {
          qr[(long)m * 512 + n] = (_Float16)yr;
          qi[(long)m * 512 + n] = (_Float16)yi;
        } else if (proj == 1) {
          kr[(long)m * 512 + n] = (_Float16)yr;
          ki[(long)m * 512 + n] = (_Float16)yi;
        } else {
          const int bb = m & 3, s = m >> 2;           // m = s*B + b
          vtr[(long)(bb * 512 + n) * 2048 + s] = (_Float16)yr;
          vti[(long)(bb * 512 + n) * 2048 + s] = (_Float16)yi;
        }
      }
  }
}

// ---------------- kernel 2: softmax pass 1 (row max m, row sumexp l) ----------------
// swapped MFMA: D[s][t] = mfma(K, Q) so each lane owns one t-row (t = lane&15).
// grid (32, 8, 4) = (T/64, H, B), block 256 (4 waves x 16 t-rows).
__global__ __launch_bounds__(256) void pass1_kernel(
    const _Float16* __restrict__ qr, const _Float16* __restrict__ qi,
    const _Float16* __restrict__ kr, const _Float16* __restrict__ ki,
    float* __restrict__ m_out, float* __restrict__ r_out) {
  const int lane = threadIdx.x & 63, wave = threadIdx.x >> 6;
  const int c = lane & 15, g = lane >> 4;
  const int t0 = blockIdx.x * 64 + wave * 16;
  const int h = blockIdx.y, b = blockIdx.z;
  const float SC2 = 0.18033688011112042f;  // log2(e)/sqrt(64)

  const long qoff = (long)((t0 + c) * 4 + b) * 512 + h * 64 + g * 8;
  const half8 qf00 = *(const half8*)(qr + qoff);
  const half8 qf01 = *(const half8*)(qi + qoff);
  const half8 qf10 = *(const half8*)(qr + qoff + 32);
  const half8 qf11 = *(const half8*)(qi + qoff + 32);

  float mrun = -1e30f, lrun = 0.0f;
  const _Float16* krp = kr + (long)(c * 4 + b) * 512 + h * 64 + g * 8;
  const _Float16* kip = ki + (long)(c * 4 + b) * 512 + h * 64 + g * 8;

  for (int s0 = 0; s0 < 2048; s0 += 32) {
    const long o0 = (long)s0 * 2048;
    const long o1 = (long)(s0 + 16) * 2048;
    half8 a00 = *(const half8*)(krp + o0);
    half8 a01 = *(const half8*)(kip + o0);
    half8 a02 = *(const half8*)(krp + o0 + 32);
    half8 a03 = *(const half8*)(kip + o0 + 32);
    half8 a10 = *(const half8*)(krp + o1);
    half8 a11 = *(const half8*)(kip + o1);
    half8 a12 = *(const half8*)(krp + o1 + 32);
    half8 a13 = *(const half8*)(kip + o1 + 32);
    f32x4 acc0 = {0.f, 0.f, 0.f, 0.f}, acc1 = {0.f, 0.f, 0.f, 0.f};
    acc0 = mfma16(a00, qf00, acc0);   // Re[QK^H] = qr*kr + qi*ki
    acc0 = mfma16(a01, qf01, acc0);
    acc0 = mfma16(a02, qf10, acc0);
    acc0 = mfma16(a03, qf11, acc0);
    acc1 = mfma16(a10, qf00, acc1);
    acc1 = mfma16(a11, qf01, acc1);
    acc1 = mfma16(a12, qf10, acc1);
    acc1 = mfma16(a13, qf11, acc1);
    float s2[8];
#pragma unroll
    for (int r = 0; r < 4; r++) { s2[r] = acc0[r] * SC2; s2[4 + r] = acc1[r] * SC2; }
    float tm = s2[0];
#pragma unroll
    for (int j = 1; j < 8; j++) tm = fmaxf(tm, s2[j]);
    const float nm = fmaxf(mrun, tm);
    float sum = 0.0f;
#pragma unroll
    for (int j = 0; j < 8; j++) sum += exp2f(s2[j] - nm);
    lrun = lrun * exp2f(mrun - nm) + sum;
    mrun = nm;
  }
  // combine the 4 lane-groups holding disjoint s-subsets of the same t-row
#pragma unroll
  for (int off = 16; off <= 32; off <<= 1) {
    const float mo = __shfl_xor(mrun, off, 64);
    const float lo = __shfl_xor(lrun, off, 64);
    const float nm = fmaxf(mrun, mo);
    lrun = lrun * exp2f(mrun - nm) + lo * exp2f(mo - nm);
    mrun = nm;
  }
  if (lane < 16) {
    const int idx = (b * 8 + h) * 2048 + t0 + c;
    m_out[idx] = mrun;
    r_out[idx] = 1.0f / lrun;
  }
}

// ---------------- kernel 3: softmax pass 2 + attn mean + PV ----------------
// grid (64, 4) = (T/32, B), block 512 = 8 waves = 8 heads.
__global__ __launch_bounds__(512, 2) void pass2_kernel(
    const _Float16* __restrict__ qr, const _Float16* __restrict__ qi,
    const _Float16* __restrict__ kr, const _Float16* __restrict__ ki,
    const _Float16* __restrict__ vtr, const _Float16* __restrict__ vti,
    const float* __restrict__ m_in, const float* __restrict__ r_in,
    _Float16* __restrict__ orh, _Float16* __restrict__ oih,
    float* __restrict__ attn) {
  __shared__ _Float16 plds[8][32][40];   // [head][t_local][s_local], stride-40 pad
  const int lane = threadIdx.x & 63, h = threadIdx.x >> 6;
  const int c = lane & 15, g = lane >> 4;
  const int t0 = blockIdx.x * 32;
  const int b = blockIdx.y;
  const float SC2 = 0.18033688011112042f;

  half8 qf[2][2][2];  // [strip][dchunk][ri]
#pragma unroll
  for (int st = 0; st < 2; st++) {
    const long qoff = (long)((t0 + st * 16 + c) * 4 + b) * 512 + h * 64 + g * 8;
    qf[st][0][0] = *(const half8*)(qr + qoff);
    qf[st][0][1] = *(const half8*)(qi + qoff);
    qf[st][1][0] = *(const half8*)(qr + qoff + 32);
    qf[st][1][1] = *(const half8*)(qi + qoff + 32);
  }
  float mrow[2][4], rrow[2][4];
#pragma unroll
  for (int st = 0; st < 2; st++)
#pragma unroll
    for (int r = 0; r < 4; r++) {
      const int idx = (b * 8 + h) * 2048 + t0 + st * 16 + g * 4 + r;
      mrow[st][r] = m_in[idx];
      rrow[st][r] = r_in[idx];
    }
  f32x4 oacc[2][4][2] = {};  // [strip][dtile][ri]
  const _Float16* krp = kr + (long)(c * 4 + b) * 512 + h * 64 + g * 8;
  const _Float16* kip = ki + (long)(c * 4 + b) * 512 + h * 64 + g * 8;
  const _Float16* vrp = vtr + (long)(b * 512 + h * 64 + c) * 2048 + g * 8;
  const _Float16* vip = vti + (long)(b * 512 + h * 64 + c) * 2048 + g * 8;

  for (int s0 = 0; s0 < 2048; s0 += 32) {
    // --- scores for this head (non-swapped: D[t][s]) ---
    half8 kf[2][2][2];  // [stile][dchunk][ri]
#pragma unroll
    for (int stile = 0; stile < 2; stile++) {
      const long koff = (long)(s0 + stile * 16) * 2048;
      kf[stile][0][0] = *(const half8*)(krp + koff);
      kf[stile][0][1] = *(const half8*)(kip + koff);
      kf[stile][1][0] = *(const half8*)(krp + koff + 32);
      kf[stile][1][1] = *(const half8*)(kip + koff + 32);
    }
    f32x4 sacc[2][2] = {};
#pragma unroll
    for (int st = 0; st < 2; st++)
#pragma unroll
      for (int stile = 0; stile < 2; stile++) {
        f32x4 a = sacc[st][stile];
        a = mfma16(qf[st][0][0], kf[stile][0][0], a);
        a = mfma16(qf[st][0][1], kf[stile][0][1], a);
        a = mfma16(qf[st][1][0], kf[stile][1][0], a);
        a = mfma16(qf[st][1][1], kf[stile][1][1], a);
        sacc[st][stile] = a;
      }
    // --- p = exp2(s*SC2 - m) * (1/l), write fp16 to LDS ---
#pragma unroll
    for (int st = 0; st < 2; st++)
#pragma unroll
      for (int stile = 0; stile < 2; stile++)
#pragma unroll
        for (int r = 0; r < 4; r++) {
          const float p = exp2f(sacc[st][stile][r] * SC2 - mrow[st][r]) * rrow[st][r];
          plds[h][st * 16 + g * 4 + r][stile * 16 + c] = (_Float16)p;
        }
    __syncthreads();
    // --- PV: A = p (from LDS, a-frag layout), B = V^T slice (contiguous) ---
    half8 vf[4][2];
#pragma unroll
    for (int dt = 0; dt < 4; dt++) {
      vf[dt][0] = *(const half8*)(vrp + (long)dt * 16 * 2048 + s0);
      vf[dt][1] = *(const half8*)(vip + (long)dt * 16 * 2048 + s0);
    }
#pragma unroll
    for (int st = 0; st < 2; st++) {
      const half8 pf = *(const half8*)(&plds[h][st * 16 + c][g * 8]);
#pragma unroll
      for (int dt = 0; dt < 4; dt++) {
        oacc[st][dt][0] = mfma16(pf, vf[dt][0], oacc[st][dt][0]);
        oacc[st][dt][1] = mfma16(pf, vf[dt][1], oacc[st][dt][1]);
      }
    }
    // --- attn_weights = mean over heads, written once (block owns (b,t,s) tile) ---
    {
      const int tt = threadIdx.x >> 4;
      const int sp = (threadIdx.x & 15) * 2;
      float a0 = 0.f, a1 = 0.f;
#pragma unroll
      for (int w = 0; w < 8; w++) {
        a0 += (float)plds[w][tt][sp];
        a1 += (float)plds[w][tt][sp + 1];
      }
      f32x2 out2 = {a0 * 0.125f, a1 * 0.125f};
      *(f32x2*)(attn + (long)(b * 2048 + t0 + tt) * 2048 + s0 + sp) = out2;
    }
    __syncthreads();
  }
  // --- epilogue: write attention output (fp16, (T*B, E) rows) ---
#pragma unroll
  for (int st = 0; st < 2; st++)
#pragma unroll
    for (int dt = 0; dt < 4; dt++)
#pragma unroll
      for (int r = 0; r < 4; r++) {
        const int t = t0 + st * 16 + g * 4 + r;
        const long row = (long)(t * 4 + b) * 512 + h * 64 + dt * 16 + c;
        orh[row] = (_Float16)oacc[st][dt][0][r];
        oih[row] = (_Float16)oacc[st][dt][1][r];
      }
}

// ---------------- kernel 4: out-projection complex GEMM (m97 structure) ----------------
// grid (64, 4), block 256. Same template as inproj but fp16 A, fp32 output + bias.
__global__ __launch_bounds__(256, 2) void outproj_kernel(
    const _Float16* __restrict__ xr, const _Float16* __restrict__ xi,   // (8192,512)
    const _Float16* __restrict__ wr, const _Float16* __restrict__ wi,   // (512,512)
    const float* __restrict__ br_, const float* __restrict__ bi_,
    float* __restrict__ outr, float* __restrict__ outi) {
  __shared__ _Float16 As_r[4096], As_i[4096];    // [128][32] f16, swizzled
  __shared__ _Float16 Bs_r[4096], Bs_i[4096];
  const int lane = threadIdx.x & 63, wave = threadIdx.x >> 6;
  const int c = lane & 15, g = lane >> 4;
  const int wrow = (wave >> 1) * 64, wcol = (wave & 1) * 64;
  const int m0 = blockIdx.x * 128, n0 = blockIdx.y * 128;

  const int bcol = ((lane & 3) ^ ((lane >> 3) & 3)) * 8;  // f16 staging col (lane const)
  const int sb = ((c >> 1) & 3) << 3;                     // f16 read swizzle

  f32x4 accR[4][4] = {};
  f32x4 accI[4][4] = {};

#pragma unroll 1
  for (int kk = 0; kk < 512; kk += 32) {
#pragma unroll
    for (int q = 0; q < 2; q++) {
      const int grp = wave * 2 + q;
      const int row = grp * 16 + (lane >> 2);
      const long ga = (long)(m0 + row) * 512 + kk + bcol;
      const long gb = (long)(n0 + row) * 512 + kk + bcol;
      gload16(xr + ga, &As_r[grp * 512]);
      gload16(xi + ga, &As_i[grp * 512]);
      gload16(wr + gb, &Bs_r[grp * 512]);
      gload16(wi + gb, &Bs_i[grp * 512]);
    }
    __syncthreads();
    half8 a_r[4], a_i[4], a_ni[4];
#pragma unroll
    for (int mt = 0; mt < 4; mt++) {
      const int arow = wrow + mt * 16 + c;
      a_r[mt] = *(const half8*)&As_r[arow * 32 + ((g * 8) ^ sb)];
      a_i[mt] = *(const half8*)&As_i[arow * 32 + ((g * 8) ^ sb)];
      a_ni[mt] = neg8(a_i[mt]);
    }
#pragma unroll
    for (int nt = 0; nt < 4; nt++) {
      const int brow = wcol + nt * 16 + c;
      const half8 bR = *(const half8*)&Bs_r[brow * 32 + ((g * 8) ^ sb)];
      const half8 bI = *(const half8*)&Bs_i[brow * 32 + ((g * 8) ^ sb)];
#pragma unroll
      for (int mt = 0; mt < 4; mt++) {
        accR[mt][nt] = mfma16(a_r[mt], bR, accR[mt][nt]);
        accR[mt][nt] = mfma16(a_ni[mt], bI, accR[mt][nt]);
        accI[mt][nt] = mfma16(a_r[mt], bI, accI[mt][nt]);
        accI[mt][nt] = mfma16(a_i[mt], bR, accI[mt][nt]);
      }
    }
    __syncthreads();
  }
#pragma unroll
  for (int nt = 0; nt < 4; nt++) {
    const int n = n0 + wcol + nt * 16 + c;
    const float vbr = br_[n], vbi = bi_[n];
#pragma unroll
    for (int mt = 0; mt < 4; mt++)
#pragma unroll
      for (int r = 0; r < 4; r++) {
        const int m = m0 + wrow + mt * 16 + g * 4 + r;
        outr[(long)m * 512 + n] = accR[mt][nt][r] + vbr;
        outi[(long)m * 512 + n] = accI[mt][nt][r] + vbi;
      }
  }
}

extern "C" void kernel_launch(void* const* d_in, const int* in_sizes, int n_in,
                              void* d_out, int out_size, void* d_ws, size_t ws_size,
                              hipStream_t stream) {
  const float* query_r = (const float*)d_in[0];
  const float* query_i = (const float*)d_in[1];
  const float* key_r   = (const float*)d_in[2];
  const float* key_i   = (const float*)d_in[3];
  const float* value_r = (const float*)d_in[4];
  const float* value_i = (const float*)d_in[5];
  const float* in_w_r  = (const float*)d_in[6];
  const float* in_w_i  = (const float*)d_in[7];
  const float* in_b_r  = (const float*)d_in[8];
  const float* in_b_i  = (const float*)d_in[9];
  const float* out_w_r = (const float*)d_in[10];
  const float* out_w_i = (const float*)d_in[11];
  const float* out_b_r = (const float*)d_in[12];
  const float* out_b_i = (const float*)d_in[13];

  // workspace layout (fp16 elements)
  _Float16* ws = (_Float16*)d_ws;
  _Float16* w16_inr  = ws;                   // 786432
  _Float16* w16_ini  = ws + 786432;          // 786432
  _Float16* w16_outr = ws + 1572864;         // 262144
  _Float16* w16_outi = ws + 1835008;         // 262144
  _Float16* qr  = ws + 2097152;              // 8 arrays x 4194304
  _Float16* qi  = qr  + 4194304;
  _Float16* kr  = qi  + 4194304;
  _Float16* ki  = kr  + 4194304;
  _Float16* vtr = ki  + 4194304;
  _Float16* vti = vtr + 4194304;
  _Float16* orh = vti + 4194304;
  _Float16* oih = orh + 4194304;
  float* m_arr = (float*)(oih + 4194304);    // 65536 fp32
  float* r_arr = m_arr + 65536;              // 65536 fp32  (total ~71.8 MB)

  float* outr = (float*)d_out;               // (T,B,E)
  float* outi = outr + 4194304;              // (T,B,E)
  float* attn = outr + 8388608;              // (B,T,S)

  cvt_weights_kernel<<<1024, 256, 0, stream>>>(in_w_r, in_w_i, out_w_r, out_w_i, ws);

  inproj_kernel<<<dim3(64, 4, 3), 256, 0, stream>>>(
      query_r, query_i, key_r, key_i, value_r, value_i,
      w16_inr, w16_ini, in_b_r, in_b_i,
      qr, qi, kr, ki, vtr, vti);

  pass1_kernel<<<dim3(32, 8, 4), 256, 0, stream>>>(qr, qi, kr, ki, m_arr, r_arr);

  pass2_kernel<<<dim3(64, 4), 512, 0, stream>>>(
      qr, qi, kr, ki, vtr, vti, m_arr, r_arr, orh, oih, attn);

  outproj_kernel<<<dim3(64, 4), 256, 0, stream>>>(
      orh, oih, w16_outr, w16_outi, out_b_r, out_b_i, outr, outi);
}

// Round 3
// 602.611 us; speedup vs baseline: 1.4837x; 1.0937x over previous
//
#include <hip/hip_runtime.h>

// Complex MultiheadAttention, fp16-MFMA implementation for gfx950.
// E=512 H=8 D=64 T=S=2048 B=4. All shapes divide tile sizes exactly.

typedef _Float16 half8 __attribute__((ext_vector_type(8)));
typedef _Float16 half2v __attribute__((ext_vector_type(2)));
typedef float f32x4 __attribute__((ext_vector_type(4)));
typedef float f32x2 __attribute__((ext_vector_type(2)));
typedef unsigned uint2v __attribute__((ext_vector_type(2)));
typedef unsigned uint4v __attribute__((ext_vector_type(4)));

__device__ __forceinline__ f32x4 mfma16(half8 a, half8 b, f32x4 c) {
  return __builtin_amdgcn_mfma_f32_16x16x32_f16(a, b, c, 0, 0, 0);
}

__device__ __forceinline__ half8 cvt8(f32x4 a, f32x4 b) {
  half8 h;
  h[0] = (_Float16)a[0]; h[1] = (_Float16)a[1]; h[2] = (_Float16)a[2]; h[3] = (_Float16)a[3];
  h[4] = (_Float16)b[0]; h[5] = (_Float16)b[1]; h[6] = (_Float16)b[2]; h[7] = (_Float16)b[3];
  return h;
}

__device__ __forceinline__ half8 neg8(half8 a) {
  half8 r;
#pragma unroll
  for (int i = 0; i < 8; i++) r[i] = -a[i];
  return r;
}

__device__ __forceinline__ unsigned pkrtz(float a, float b) {
  return __builtin_bit_cast(unsigned, __builtin_amdgcn_cvt_pkrtz(a, b));
}

__device__ __forceinline__ void gload16(const void* g, void* l) {
  __builtin_amdgcn_global_load_lds((const __attribute__((address_space(1))) void*)g,
                                   (__attribute__((address_space(3))) void*)l, 16, 0, 0);
}

// ---------------- kernel 0: convert weights fp32 -> fp16 into ws ----------------
__global__ __launch_bounds__(256) void cvt_weights_kernel(
    const float* __restrict__ iwr, const float* __restrict__ iwi,
    const float* __restrict__ owr, const float* __restrict__ owi,
    _Float16* __restrict__ dst) {
  const int i = blockIdx.x * 256 + threadIdx.x;  // 262144 threads, 8 elems each
  const float* src;
  long so, doff;
  if (i < 98304)       { src = iwr; so = (long)i * 8;            doff = so; }
  else if (i < 196608) { src = iwi; so = (long)(i - 98304) * 8;  doff = 786432 + so; }
  else if (i < 229376) { src = owr; so = (long)(i - 196608) * 8; doff = 1572864 + so; }
  else                 { src = owi; so = (long)(i - 229376) * 8; doff = 1835008 + so; }
  f32x4 a = *(const f32x4*)(src + so);
  f32x4 b = *(const f32x4*)(src + so + 4);
  *(half8*)(dst + doff) = cvt8(a, b);
}

// ---------------- kernel 1: in-projection complex GEMM (m97 structure) ----------------
__global__ __launch_bounds__(256, 2) void inproj_kernel(
    const float* __restrict__ xqr, const float* __restrict__ xqi,
    const float* __restrict__ xkr, const float* __restrict__ xki,
    const float* __restrict__ xvr, const float* __restrict__ xvi,
    const _Float16* __restrict__ wr, const _Float16* __restrict__ wi,   // (1536,512) fp16
    const float* __restrict__ br_, const float* __restrict__ bi_,      // (1536)
    _Float16* __restrict__ qr, _Float16* __restrict__ qi,              // (8192,512)
    _Float16* __restrict__ kr, _Float16* __restrict__ ki,              // (8192,512)
    _Float16* __restrict__ vtr, _Float16* __restrict__ vti) {          // (B,E,S) transposed
  __shared__ float As_r[4096], As_i[4096];       // [128][32] f32, swizzled
  __shared__ _Float16 Bs_r[4096], Bs_i[4096];    // [128][32] f16, swizzled
  const int proj = blockIdx.z;
  const float* xr = (proj == 0) ? xqr : (proj == 1) ? xkr : xvr;
  const float* xi = (proj == 0) ? xqi : (proj == 1) ? xki : xvi;
  const int lane = threadIdx.x & 63, wave = threadIdx.x >> 6;
  const int c = lane & 15, g = lane >> 4;
  const int wrow = (wave >> 1) * 64, wcol = (wave & 1) * 64;
  const int m0 = blockIdx.x * 128, n0 = blockIdx.y * 128;

  const int acol = ((lane & 7) ^ (lane >> 3)) * 4;        // f32 units
  const int bcol = ((lane & 3) ^ ((lane >> 3) & 3)) * 8;  // f16 units
  const int sa = (c & 7) << 2;                            // f32 units
  const int sb = ((c >> 1) & 3) << 3;                     // f16 units

  f32x4 accR[4][4] = {};
  f32x4 accI[4][4] = {};

#pragma unroll 1
  for (int kk = 0; kk < 512; kk += 32) {
#pragma unroll
    for (int q = 0; q < 4; q++) {
      const int grp = wave * 4 + q;
      const int arow = grp * 8 + (lane >> 3);
      const long go = (long)(m0 + arow) * 512 + kk + acol;
      gload16(xr + go, &As_r[grp * 256]);
      gload16(xi + go, &As_i[grp * 256]);
    }
#pragma unroll
    for (int q = 0; q < 2; q++) {
      const int grp = wave * 2 + q;
      const int brow = grp * 16 + (lane >> 2);
      const long go = (long)(proj * 512 + n0 + brow) * 512 + kk + bcol;
      gload16(wr + go, &Bs_r[grp * 512]);
      gload16(wi + go, &Bs_i[grp * 512]);
    }
    __syncthreads();
    half8 a_r[4], a_i[4], a_ni[4];
#pragma unroll
    for (int mt = 0; mt < 4; mt++) {
      const int arow = wrow + mt * 16 + c;
      f32x4 lo = *(const f32x4*)&As_r[arow * 32 + ((g * 8) ^ sa)];
      f32x4 hi = *(const f32x4*)&As_r[arow * 32 + ((g * 8 + 4) ^ sa)];
      a_r[mt] = cvt8(lo, hi);
      lo = *(const f32x4*)&As_i[arow * 32 + ((g * 8) ^ sa)];
      hi = *(const f32x4*)&As_i[arow * 32 + ((g * 8 + 4) ^ sa)];
      a_i[mt] = cvt8(lo, hi);
      a_ni[mt] = neg8(a_i[mt]);
    }
#pragma unroll
    for (int nt = 0; nt < 4; nt++) {
      const int brow = wcol + nt * 16 + c;
      const half8 bR = *(const half8*)&Bs_r[brow * 32 + ((g * 8) ^ sb)];
      const half8 bI = *(const half8*)&Bs_i[brow * 32 + ((g * 8) ^ sb)];
#pragma unroll
      for (int mt = 0; mt < 4; mt++) {
        accR[mt][nt] = mfma16(a_r[mt], bR, accR[mt][nt]);
        accR[mt][nt] = mfma16(a_ni[mt], bI, accR[mt][nt]);  // yr = xr*wr - xi*wi
        accI[mt][nt] = mfma16(a_r[mt], bI, accI[mt][nt]);
        accI[mt][nt] = mfma16(a_i[mt], bR, accI[mt][nt]);   // yi = xr*wi + xi*wr
      }
    }
    __syncthreads();
  }
#pragma unroll
  for (int nt = 0; nt < 4; nt++) {
    const int n = n0 + wcol + nt * 16 + c;
    const float vbr = br_[proj * 512 + n];
    const float vbi = bi_[proj * 512 + n];
#pragma unroll
    for (int mt = 0; mt < 4; mt++)
#pragma unroll
      for (int r = 0; r < 4; r++) {
        const int m = m0 + wrow + mt * 16 + g * 4 + r;
        const float yr = accR[mt][nt][r] + vbr;
        const float yi = accI[mt][nt][r] + vbi;
        if (proj == 0) {
          qr[(long)m * 512 + n] = (_Float16)yr;
          qi[(long)m * 512 + n] = (_Float16)yi;
        } else if (proj == 1) {
          kr[(long)m * 512 + n] = (_Float16)yr;
          ki[(long)m * 512 + n] = (_Float16)yi;
        } else {
          const int bb = m & 3, s = m >> 2;           // m = s*B + b
          vtr[(long)(bb * 512 + n) * 2048 + s] = (_Float16)yr;
          vti[(long)(bb * 512 + n) * 2048 + s] = (_Float16)yi;
        }
      }
  }
}

// ---------------- kernel 2: softmax pass 1 (row max m, row 1/sumexp) ----------------
__global__ __launch_bounds__(256) void pass1_kernel(
    const _Float16* __restrict__ qr, const _Float16* __restrict__ qi,
    const _Float16* __restrict__ kr, const _Float16* __restrict__ ki,
    float* __restrict__ m_out, float* __restrict__ r_out) {
  const int lane = threadIdx.x & 63, wave = threadIdx.x >> 6;
  const int c = lane & 15, g = lane >> 4;
  const int t0 = blockIdx.x * 64 + wave * 16;
  const int h = blockIdx.y, b = blockIdx.z;
  const float SC2 = 0.18033688011112042f;  // log2(e)/sqrt(64)

  const long qoff = (long)((t0 + c) * 4 + b) * 512 + h * 64 + g * 8;
  const half8 qf00 = *(const half8*)(qr + qoff);
  const half8 qf01 = *(const half8*)(qi + qoff);
  const half8 qf10 = *(const half8*)(qr + qoff + 32);
  const half8 qf11 = *(const half8*)(qi + qoff + 32);

  float mrun = -1e30f, lrun = 0.0f;
  const _Float16* krp = kr + (long)(c * 4 + b) * 512 + h * 64 + g * 8;
  const _Float16* kip = ki + (long)(c * 4 + b) * 512 + h * 64 + g * 8;

  for (int s0 = 0; s0 < 2048; s0 += 32) {
    const long o0 = (long)s0 * 2048;
    const long o1 = (long)(s0 + 16) * 2048;
    half8 a00 = *(const half8*)(krp + o0);
    half8 a01 = *(const half8*)(kip + o0);
    half8 a02 = *(const half8*)(krp + o0 + 32);
    half8 a03 = *(const half8*)(kip + o0 + 32);
    half8 a10 = *(const half8*)(krp + o1);
    half8 a11 = *(const half8*)(kip + o1);
    half8 a12 = *(const half8*)(krp + o1 + 32);
    half8 a13 = *(const half8*)(kip + o1 + 32);
    f32x4 acc0 = {0.f, 0.f, 0.f, 0.f}, acc1 = {0.f, 0.f, 0.f, 0.f};
    acc0 = mfma16(a00, qf00, acc0);   // Re[QK^H] = qr*kr + qi*ki
    acc0 = mfma16(a01, qf01, acc0);
    acc0 = mfma16(a02, qf10, acc0);
    acc0 = mfma16(a03, qf11, acc0);
    acc1 = mfma16(a10, qf00, acc1);
    acc1 = mfma16(a11, qf01, acc1);
    acc1 = mfma16(a12, qf10, acc1);
    acc1 = mfma16(a13, qf11, acc1);
    float s2[8];
#pragma unroll
    for (int r = 0; r < 4; r++) { s2[r] = acc0[r] * SC2; s2[4 + r] = acc1[r] * SC2; }
    float tm = s2[0];
#pragma unroll
    for (int j = 1; j < 8; j++) tm = fmaxf(tm, s2[j]);
    const float nm = fmaxf(mrun, tm);
    float sum = 0.0f;
#pragma unroll
    for (int j = 0; j < 8; j++) sum += exp2f(s2[j] - nm);
    lrun = lrun * exp2f(mrun - nm) + sum;
    mrun = nm;
  }
#pragma unroll
  for (int off = 16; off <= 32; off <<= 1) {
    const float mo = __shfl_xor(mrun, off, 64);
    const float lo = __shfl_xor(lrun, off, 64);
    const float nm = fmaxf(mrun, mo);
    lrun = lrun * exp2f(mrun - nm) + lo * exp2f(mo - nm);
    mrun = nm;
  }
  if (lane < 16) {
    const int idx = (b * 8 + h) * 2048 + t0 + c;
    m_out[idx] = mrun;
    r_out[idx] = 1.0f / lrun;
  }
}

// ---------------- kernel 3: softmax pass 2 + attn mean + PV ----------------
// Swapped-QK^T: lane owns t-row (t=c per 16-t strip); p stays in registers.
// Repack to PV A-frag via cvt_pkrtz + permlane32_swap + permlane16_swap.
// p hits LDS only for the cross-head mean (1 ds_write_b128/strip, dbuf, 1 barrier/iter).
__device__ __forceinline__ void load_kswap(half8 (&kf)[8],
    const _Float16* krp0, const _Float16* kip0, int s) {
#pragma unroll
  for (int sq = 0; sq < 2; sq++)
#pragma unroll
    for (int ch = 0; ch < 2; ch++) {
      const long o = (long)(s + sq * 16) * 2048 + ch * 32;
      kf[sq * 4 + ch * 2 + 0] = *(const half8*)(krp0 + o);
      kf[sq * 4 + ch * 2 + 1] = *(const half8*)(kip0 + o);
    }
}

__device__ __forceinline__ void load_vv(half8 (&vf)[8],
    const _Float16* vrp, const _Float16* vip, int s) {
#pragma unroll
  for (int dt = 0; dt < 4; dt++) {
    vf[dt * 2 + 0] = *(const half8*)(vrp + (long)dt * 16 * 2048 + s);
    vf[dt * 2 + 1] = *(const half8*)(vip + (long)dt * 16 * 2048 + s);
  }
}

__device__ __forceinline__ void p2_step(
    int s0, _Float16* pbuf, const half8 (&kf)[8], const half8 (&vf)[8],
    const half8 (&qf)[8], float nm0, float r0, float nm1, float r1,
    f32x4 (&oacc)[2][4][2], float* attn_base,
    int c, int g, int h, int tid) {
  const float SC2 = 0.18033688011112042f;
  // ---- scores (swapped): D[s_local][t=c] ----
  f32x4 sacc[2][2];
#pragma unroll
  for (int st = 0; st < 2; st++)
#pragma unroll
    for (int sq = 0; sq < 2; sq++) {
      f32x4 a = {0.f, 0.f, 0.f, 0.f};
      a = mfma16(kf[sq * 4 + 0], qf[st * 4 + 0], a);
      a = mfma16(kf[sq * 4 + 1], qf[st * 4 + 1], a);
      a = mfma16(kf[sq * 4 + 2], qf[st * 4 + 2], a);
      a = mfma16(kf[sq * 4 + 3], qf[st * 4 + 3], a);
      sacc[st][sq] = a;
    }
  // ---- softmax + repack to PV A-fragments ----
  half8 pa0, pa1;
#pragma unroll
  for (int st = 0; st < 2; st++) {
    const float nm = st ? nm1 : nm0;
    const float rv = st ? r1 : r0;
    float p[8];
#pragma unroll
    for (int r = 0; r < 4; r++) {
      p[r]     = exp2f(fmaf(sacc[st][0][r], SC2, nm)) * rv;  // s_local = 4g+r
      p[4 + r] = exp2f(fmaf(sacc[st][1][r], SC2, nm)) * rv;  // s_local = 16+4g+r
    }
    const unsigned X0 = pkrtz(p[0], p[1]), X1 = pkrtz(p[2], p[3]);
    const unsigned Y0 = pkrtz(p[4], p[5]), Y1 = pkrtz(p[6], p[7]);
    const uint2v ab0 = __builtin_amdgcn_permlane32_swap(X0, Y0, false, false);
    const uint2v ab1 = __builtin_amdgcn_permlane32_swap(X1, Y1, false, false);
    const uint2v cd0 = __builtin_amdgcn_permlane16_swap(ab0[0], ab0[1], false, false);
    const uint2v cd1 = __builtin_amdgcn_permlane16_swap(ab1[0], ab1[1], false, false);
    uint4v u;
    u[0] = cd0[0]; u[1] = cd1[0]; u[2] = cd0[1]; u[3] = cd1[1];
    const half8 pav = __builtin_bit_cast(half8, u);   // p[t=c][s0 + g*8 .. g*8+7]
    if (st == 0) pa0 = pav; else pa1 = pav;
    // stash for cross-head mean: row = st*16+c, cols 8g..8g+7
    *(half8*)(pbuf + (h * 32 + st * 16 + c) * 40 + g * 8) = pav;
  }
  __syncthreads();
  // ---- PV from registers ----
#pragma unroll
  for (int dt = 0; dt < 4; dt++) {
    oacc[0][dt][0] = mfma16(pa0, vf[dt * 2 + 0], oacc[0][dt][0]);
    oacc[0][dt][1] = mfma16(pa0, vf[dt * 2 + 1], oacc[0][dt][1]);
    oacc[1][dt][0] = mfma16(pa1, vf[dt * 2 + 0], oacc[1][dt][0]);
    oacc[1][dt][1] = mfma16(pa1, vf[dt * 2 + 1], oacc[1][dt][1]);
  }
  // ---- attn mean over heads (thread owns one (t, s-pair)) ----
  {
    const _Float16* mp = pbuf + (tid >> 4) * 40 + (tid & 15) * 2;
    float a0 = 0.f, a1 = 0.f;
#pragma unroll
    for (int w = 0; w < 8; w++) {
      const half2v v = *(const half2v*)(mp + w * 1280);
      a0 += (float)v[0];
      a1 += (float)v[1];
    }
    f32x2 out2 = {a0 * 0.125f, a1 * 0.125f};
    *(f32x2*)(attn_base + s0) = out2;
  }
}

__global__ __launch_bounds__(512, 2) void pass2_kernel(
    const _Float16* __restrict__ qr, const _Float16* __restrict__ qi,
    const _Float16* __restrict__ kr, const _Float16* __restrict__ ki,
    const _Float16* __restrict__ vtr, const _Float16* __restrict__ vti,
    const float* __restrict__ m_in, const float* __restrict__ r_in,
    _Float16* __restrict__ orh, _Float16* __restrict__ oih,
    float* __restrict__ attn) {
  __shared__ _Float16 plds[2][8][32][40];   // dbuf p tiles, 40 KB
  const int tid = threadIdx.x;
  const int lane = tid & 63, h = tid >> 6;
  const int c = lane & 15, g = lane >> 4;
  const int t0 = blockIdx.x * 32;
  const int b = blockIdx.y;

  // Q fragments (B-operand of swapped QK^T; same layout as row-major load)
  half8 qf[8];
#pragma unroll
  for (int st = 0; st < 2; st++) {
    const long qoff = (long)((t0 + st * 16 + c) * 4 + b) * 512 + h * 64 + g * 8;
    qf[st * 4 + 0] = *(const half8*)(qr + qoff);
    qf[st * 4 + 1] = *(const half8*)(qi + qoff);
    qf[st * 4 + 2] = *(const half8*)(qr + qoff + 32);
    qf[st * 4 + 3] = *(const half8*)(qi + qoff + 32);
  }
  const int midx = (b * 8 + h) * 2048 + t0 + c;
  const float nm0 = -m_in[midx],      rr0 = r_in[midx];
  const float nm1 = -m_in[midx + 16], rr1 = r_in[midx + 16];

  f32x4 oacc[2][4][2] = {};
  const _Float16* krp0 = kr + (long)(c * 4 + b) * 512 + h * 64 + g * 8;
  const _Float16* kip0 = ki + (long)(c * 4 + b) * 512 + h * 64 + g * 8;
  const _Float16* vrp = vtr + (long)(b * 512 + h * 64 + c) * 2048 + g * 8;
  const _Float16* vip = vti + (long)(b * 512 + h * 64 + c) * 2048 + g * 8;
  float* attn_base = attn + ((long)b * 2048 + t0 + (tid >> 4)) * 2048 + (tid & 15) * 2;
  _Float16* pb0 = &plds[0][0][0][0];
  _Float16* pb1 = &plds[1][0][0][0];

  half8 kfA[8], kfB[8], vf[8];
  load_kswap(kfA, krp0, kip0, 0);
  load_vv(vf, vrp, vip, 0);

#pragma unroll 1
  for (int s0 = 0; s0 < 2048; s0 += 64) {
    load_kswap(kfB, krp0, kip0, s0 + 32);
    p2_step(s0, pb0, kfA, vf, qf, nm0, rr0, nm1, rr1, oacc, attn_base, c, g, h, tid);
    load_vv(vf, vrp, vip, s0 + 32);
    load_kswap(kfA, krp0, kip0, (s0 + 64) & 2047);
    p2_step(s0 + 32, pb1, kfB, vf, qf, nm0, rr0, nm1, rr1, oacc, attn_base, c, g, h, tid);
    load_vv(vf, vrp, vip, (s0 + 64) & 2047);
  }
  // ---- epilogue: write attention output (fp16, (T*B, E) rows) ----
#pragma unroll
  for (int st = 0; st < 2; st++)
#pragma unroll
    for (int dt = 0; dt < 4; dt++)
#pragma unroll
      for (int r = 0; r < 4; r++) {
        const int t = t0 + st * 16 + g * 4 + r;
        const long row = (long)(t * 4 + b) * 512 + h * 64 + dt * 16 + c;
        orh[row] = (_Float16)oacc[st][dt][0][r];
        oih[row] = (_Float16)oacc[st][dt][1][r];
      }
}

// ---------------- kernel 4: out-projection complex GEMM (m97 structure) ----------------
__global__ __launch_bounds__(256, 2) void outproj_kernel(
    const _Float16* __restrict__ xr, const _Float16* __restrict__ xi,   // (8192,512)
    const _Float16* __restrict__ wr, const _Float16* __restrict__ wi,   // (512,512)
    const float* __restrict__ br_, const float* __restrict__ bi_,
    float* __restrict__ outr, float* __restrict__ outi) {
  __shared__ _Float16 As_r[4096], As_i[4096];    // [128][32] f16, swizzled
  __shared__ _Float16 Bs_r[4096], Bs_i[4096];
  const int lane = threadIdx.x & 63, wave = threadIdx.x >> 6;
  const int c = lane & 15, g = lane >> 4;
  const int wrow = (wave >> 1) * 64, wcol = (wave & 1) * 64;
  const int m0 = blockIdx.x * 128, n0 = blockIdx.y * 128;

  const int bcol = ((lane & 3) ^ ((lane >> 3) & 3)) * 8;  // f16 staging col (lane const)
  const int sb = ((c >> 1) & 3) << 3;                     // f16 read swizzle

  f32x4 accR[4][4] = {};
  f32x4 accI[4][4] = {};

#pragma unroll 1
  for (int kk = 0; kk < 512; kk += 32) {
#pragma unroll
    for (int q = 0; q < 2; q++) {
      const int grp = wave * 2 + q;
      const int row = grp * 16 + (lane >> 2);
      const long ga = (long)(m0 + row) * 512 + kk + bcol;
      const long gb = (long)(n0 + row) * 512 + kk + bcol;
      gload16(xr + ga, &As_r[grp * 512]);
      gload16(xi + ga, &As_i[grp * 512]);
      gload16(wr + gb, &Bs_r[grp * 512]);
      gload16(wi + gb, &Bs_i[grp * 512]);
    }
    __syncthreads();
    half8 a_r[4], a_i[4], a_ni[4];
#pragma unroll
    for (int mt = 0; mt < 4; mt++) {
      const int arow = wrow + mt * 16 + c;
      a_r[mt] = *(const half8*)&As_r[arow * 32 + ((g * 8) ^ sb)];
      a_i[mt] = *(const half8*)&As_i[arow * 32 + ((g * 8) ^ sb)];
      a_ni[mt] = neg8(a_i[mt]);
    }
#pragma unroll
    for (int nt = 0; nt < 4; nt++) {
      const int brow = wcol + nt * 16 + c;
      const half8 bR = *(const half8*)&Bs_r[brow * 32 + ((g * 8) ^ sb)];
      const half8 bI = *(const half8*)&Bs_i[brow * 32 + ((g * 8) ^ sb)];
#pragma unroll
      for (int mt = 0; mt < 4; mt++) {
        accR[mt][nt] = mfma16(a_r[mt], bR, accR[mt][nt]);
        accR[mt][nt] = mfma16(a_ni[mt], bI, accR[mt][nt]);
        accI[mt][nt] = mfma16(a_r[mt], bI, accI[mt][nt]);
        accI[mt][nt] = mfma16(a_i[mt], bR, accI[mt][nt]);
      }
    }
    __syncthreads();
  }
#pragma unroll
  for (int nt = 0; nt < 4; nt++) {
    const int n = n0 + wcol + nt * 16 + c;
    const float vbr = br_[n], vbi = bi_[n];
#pragma unroll
    for (int mt = 0; mt < 4; mt++)
#pragma unroll
      for (int r = 0; r < 4; r++) {
        const int m = m0 + wrow + mt * 16 + g * 4 + r;
        outr[(long)m * 512 + n] = accR[mt][nt][r] + vbr;
        outi[(long)m * 512 + n] = accI[mt][nt][r] + vbi;
      }
  }
}

extern "C" void kernel_launch(void* const* d_in, const int* in_sizes, int n_in,
                              void* d_out, int out_size, void* d_ws, size_t ws_size,
                              hipStream_t stream) {
  const float* query_r = (const float*)d_in[0];
  const float* query_i = (const float*)d_in[1];
  const float* key_r   = (const float*)d_in[2];
  const float* key_i   = (const float*)d_in[3];
  const float* value_r = (const float*)d_in[4];
  const float* value_i = (const float*)d_in[5];
  const float* in_w_r  = (const float*)d_in[6];
  const float* in_w_i  = (const float*)d_in[7];
  const float* in_b_r  = (const float*)d_in[8];
  const float* in_b_i  = (const float*)d_in[9];
  const float* out_w_r = (const float*)d_in[10];
  const float* out_w_i = (const float*)d_in[11];
  const float* out_b_r = (const float*)d_in[12];
  const float* out_b_i = (const float*)d_in[13];

  // workspace layout (fp16 elements)
  _Float16* ws = (_Float16*)d_ws;
  _Float16* w16_inr  = ws;                   // 786432
  _Float16* w16_ini  = ws + 786432;          // 786432
  _Float16* w16_outr = ws + 1572864;         // 262144
  _Float16* w16_outi = ws + 1835008;         // 262144
  _Float16* qr  = ws + 2097152;              // 8 arrays x 4194304
  _Float16* qi  = qr  + 4194304;
  _Float16* kr  = qi  + 4194304;
  _Float16* ki  = kr  + 4194304;
  _Float16* vtr = ki  + 4194304;
  _Float16* vti = vtr + 4194304;
  _Float16* orh = vti + 4194304;
  _Float16* oih = orh + 4194304;
  float* m_arr = (float*)(oih + 4194304);    // 65536 fp32
  float* r_arr = m_arr + 65536;              // 65536 fp32  (total ~71.8 MB)

  float* outr = (float*)d_out;               // (T,B,E)
  float* outi = outr + 4194304;              // (T,B,E)
  float* attn = outr + 8388608;              // (B,T,S)

  cvt_weights_kernel<<<1024, 256, 0, stream>>>(in_w_r, in_w_i, out_w_r, out_w_i, ws);

  inproj_kernel<<<dim3(64, 4, 3), 256, 0, stream>>>(
      query_r, query_i, key_r, key_i, value_r, value_i,
      w16_inr, w16_ini, in_b_r, in_b_i,
      qr, qi, kr, ki, vtr, vti);

  pass1_kernel<<<dim3(32, 8, 4), 256, 0, stream>>>(qr, qi, kr, ki, m_arr, r_arr);

  pass2_kernel<<<dim3(64, 4), 512, 0, stream>>>(
      qr, qi, kr, ki, vtr, vti, m_arr, r_arr, orh, oih, attn);

  outproj_kernel<<<dim3(64, 4), 256, 0, stream>>>(
      orh, oih, w16_outr, w16_outi, out_b_r, out_b_i, outr, outi);
}